// Round 4
// baseline (159.759 us; speedup 1.0000x reference)
//
#include <hip/hip_runtime.h>
#include <hip/hip_bf16.h>

// Net_27358941675610: the 50-step scan collapses to its fixed point:
//   R   = 0.35*sigmoid((6/7)*(psp^T @ W_h^T + b_h))            [4096,2048]
//   out = 0.35*sigmoid(0.75*(R @ W_o^T + b_o) + 0.125*label)   [4096,512]
// (0.3^50 / 0.2^50 transients < 1e-25.) Inputs fp32, output fp32.
// R4: 8-wave 128x128 tiles (2 blk/CU -> 16 waves/CU), XOR bank swizzle,
//     split-K x4 GEMM2 with fp32 atomics + fused reduce epilogue.

typedef __bf16 bf16_t;
typedef __bf16 bf16x8 __attribute__((ext_vector_type(8)));
typedef __bf16 bf16x4v __attribute__((ext_vector_type(4)));
typedef float f32x4 __attribute__((ext_vector_type(4)));

#define GLD_TO_LDS16(gp, lp)                                            \
  __builtin_amdgcn_global_load_lds(                                     \
      (__attribute__((address_space(1))) void*)(void*)(gp),             \
      (__attribute__((address_space(3))) void*)(lp), 16, 0, 0)

// ---- psp fp32 [R][C] -> pspT bf16 [C][R], 64x64 tiles --------------------
__global__ __launch_bounds__(256) void transpose_cvt(
    const float* __restrict__ in, bf16_t* __restrict__ out, int R, int C) {
  __shared__ float tile[64][65];
  const int tx = threadIdx.x & 63;
  const int ty = threadIdx.x >> 6;
  const int r0 = blockIdx.y * 64;
  const int c0 = blockIdx.x * 64;
#pragma unroll
  for (int i = 0; i < 16; ++i) {
    const int r = ty + i * 4;
    tile[r][tx] = in[(size_t)(r0 + r) * C + c0 + tx];
  }
  __syncthreads();
#pragma unroll
  for (int i = 0; i < 16; ++i) {
    const int r = ty + i * 4;
    out[(size_t)(c0 + r) * R + r0 + tx] = (bf16_t)tile[tx][r];
  }
}

// ---- both weight matrices fp32 -> bf16, one launch -----------------------
__global__ __launch_bounds__(256) void cvt2_f32_bf16(
    const float4* __restrict__ w1, bf16x4v* __restrict__ o1, int n1,
    const float4* __restrict__ w2, bf16x4v* __restrict__ o2, int n2) {
  const int i = blockIdx.x * 256 + threadIdx.x;
  const float4 v = (i < n1) ? w1[i] : w2[i - n1];
  bf16x4v o;
  o.x = (bf16_t)v.x; o.y = (bf16_t)v.y; o.z = (bf16_t)v.z; o.w = (bf16_t)v.w;
  if (i < n1) o1[i] = o;
  else if (i - n1 < n2) o2[i - n1] = o;
}

// ---- NT GEMM template: 128x128 tile, 8 waves of 64x32, BK=32 -------------
// LDS slot (row, s') holds global 16B-seg s' ^ ((row>>1)&3)  (bank swizzle).
// MODE 1: C(bf16) = 0.35*sigmoid((6/7)*(acc + bias[n]))
// MODE 2: atomicAdd fp32 partial into P[m*N+n] (split-K over blockIdx.z)
template <int MODE>
__global__ __launch_bounds__(512, 4) void gemm_nt(
    const bf16_t* __restrict__ A, const bf16_t* __restrict__ Bt,
    const float* __restrict__ bias, void* __restrict__ Cout,
    int M, int N, int K, int kc) {
  constexpr int BM = 128, BN = 128, BK = 32;
  constexpr int WTM = 4, WTN = 2;
  __shared__ __align__(16) bf16_t sA[BM * BK];
  __shared__ __align__(16) bf16_t sB[BN * BK];

  const int tid = threadIdx.x;
  const int wave = tid >> 6;  // 0..7
  const int lane = tid & 63;
  const int bm = blockIdx.x * BM;
  const int bn = blockIdx.y * BN;
  const int kbase = blockIdx.z * kc;
  const int wm = (wave & 1) * 64;
  const int wn = (wave >> 1) * 32;

  f32x4 acc[WTM][WTN] = {};

  // staging: wave w stages the 16-row chunk w of A and of B (1 KB each);
  // lane l -> LDS offset l*16B = row (l>>2), slot (l&3) of the chunk.
  const int arow = wave * 16 + (lane >> 2);        // row within 128-row tile
  const int sseg = (lane & 3) ^ ((arow >> 1) & 3); // swizzled global segment
  const bf16_t* Ag = A + (size_t)(bm + arow) * K + kbase + sseg * 8;
  const bf16_t* Bg = Bt + (size_t)(bn + arow) * K + kbase + sseg * 8;
  bf16_t* sAw = sA + wave * (16 * BK);
  bf16_t* sBw = sB + wave * (16 * BK);

  const int fr = lane & 15;  // m/n within a 16-fragment
  const int q = lane >> 4;   // k segment 0..3 (k = q*8 .. q*8+7)

  for (int k0 = 0; k0 < kc; k0 += BK) {
    GLD_TO_LDS16(Ag + k0, sAw);
    GLD_TO_LDS16(Bg + k0, sBw);
    __syncthreads();

    bf16x8 af[WTM], bfr[WTN];
#pragma unroll
    for (int i = 0; i < WTM; ++i) {
      const int rr = wm + i * 16 + fr;
      af[i] = *(const bf16x8*)(sA + rr * BK + ((q ^ ((rr >> 1) & 3)) * 8));
    }
#pragma unroll
    for (int j = 0; j < WTN; ++j) {
      const int rr = wn + j * 16 + fr;
      bfr[j] = *(const bf16x8*)(sB + rr * BK + ((q ^ ((rr >> 1) & 3)) * 8));
    }
#pragma unroll
    for (int i = 0; i < WTM; ++i)
#pragma unroll
      for (int j = 0; j < WTN; ++j)
        acc[i][j] =
            __builtin_amdgcn_mfma_f32_16x16x32_bf16(af[i], bfr[j], acc[i][j], 0, 0, 0);
    __syncthreads();
  }

  // epilogue: C/D layout col = lane&15, row = (lane>>4)*4 + r  (m89)
  const int cm0 = (lane >> 4) * 4;
#pragma unroll
  for (int j = 0; j < WTN; ++j) {
    const int gn = bn + wn + j * 16 + fr;
    const float bj = (MODE == 1) ? bias[gn] : 0.0f;
#pragma unroll
    for (int i = 0; i < WTM; ++i) {
#pragma unroll
      for (int r = 0; r < 4; ++r) {
        const int gm = bm + wm + i * 16 + cm0 + r;
        if (MODE == 1) {
          const float z = 0.8571428571428571f * (acc[i][j][r] + bj);
          ((bf16_t*)Cout)[(size_t)gm * N + gn] =
              (bf16_t)(0.35f / (1.0f + __expf(-z)));
        } else {
          atomicAdd((float*)Cout + (size_t)gm * N + gn, acc[i][j][r]);
        }
      }
    }
  }
}

// ---- out = 0.35*sigmoid(0.75*(P + b_o[n]) + 0.125*label), float4 ---------
__global__ __launch_bounds__(256) void reduce_out(
    const float4* __restrict__ P, const float4* __restrict__ lbl,
    const float* __restrict__ b_o, float4* __restrict__ out, int n4, int N4) {
  const int i = blockIdx.x * 256 + threadIdx.x;
  if (i >= n4) return;
  const int nb = (i % N4) * 4;
  const float4 p = P[i];
  const float4 l = lbl[i];
  float4 o;
  float z;
  z = 0.75f * (p.x + b_o[nb + 0]) + 0.125f * l.x; o.x = 0.35f / (1.0f + __expf(-z));
  z = 0.75f * (p.y + b_o[nb + 1]) + 0.125f * l.y; o.y = 0.35f / (1.0f + __expf(-z));
  z = 0.75f * (p.z + b_o[nb + 2]) + 0.125f * l.z; o.z = 0.35f / (1.0f + __expf(-z));
  z = 0.75f * (p.w + b_o[nb + 3]) + 0.125f * l.w; o.w = 0.35f / (1.0f + __expf(-z));
  out[i] = o;
}

extern "C" void kernel_launch(void* const* d_in, const int* in_sizes, int n_in,
                              void* d_out, int out_size, void* d_ws, size_t ws_size,
                              hipStream_t stream) {
  constexpr int IN = 1024, HID = 2048, OUT = 512, B = 4096;
  const float* psp = (const float*)d_in[0];   // [IN, B]
  const float* lbl = (const float*)d_in[1];   // [B, OUT]
  const float* W_h = (const float*)d_in[2];   // [HID, IN]
  const float* b_h = (const float*)d_in[3];   // [HID]
  const float* W_o = (const float*)d_in[4];   // [OUT, HID]
  const float* b_o = (const float*)d_in[5];   // [OUT]
  float* out = (float*)d_out;                 // [B, OUT] fp32

  // ws layout (30 MB total, same footprint as the passing R3):
  // [Whb 4MB][Wob 2MB][pspT 8MB | P 8MB (pspT dead after GEMM1)][Rm 16MB]
  bf16_t* Whb = (bf16_t*)d_ws;                 // [HID, IN]
  bf16_t* Wob = Whb + (size_t)HID * IN;        // [OUT, HID]
  bf16_t* pspT = Wob + (size_t)OUT * HID;      // [B, IN]
  float* P = (float*)pspT;                     // [B, OUT] fp32 (aliases pspT)
  bf16_t* Rm = pspT + (size_t)B * IN;          // [B, HID]

  // psp [IN,B] fp32 -> pspT [B,IN] bf16
  transpose_cvt<<<dim3(B / 64, IN / 64), 256, 0, stream>>>(psp, pspT, IN, B);
  // both weights fp32 -> bf16 in one launch
  {
    const int n1 = HID * IN / 4, n2 = OUT * HID / 4;
    cvt2_f32_bf16<<<(n1 + n2 + 255) / 256, 256, 0, stream>>>(
        (const float4*)W_h, (bf16x4v*)Whb, n1,
        (const float4*)W_o, (bf16x4v*)Wob, n2);
  }
  // R = 0.35*sigmoid((6/7)*(pspT @ W_h^T + b_h))  [bf16]
  gemm_nt<1><<<dim3(B / 128, HID / 128, 1), 512, 0, stream>>>(
      pspT, Whb, b_h, Rm, B, HID, IN, IN);
  // zero split-K accumulator (pspT region is dead now)
  hipMemsetAsync(P, 0, (size_t)B * OUT * sizeof(float), stream);
  // P += R @ W_o^T  (split-K x4, fp32 atomics)
  gemm_nt<2><<<dim3(B / 128, OUT / 128, 4), 512, 0, stream>>>(
      Rm, Wob, nullptr, P, B, OUT, HID, HID / 4);
  // out = 0.35*sigmoid(0.75*(P + b_o) + 0.125*label)
  reduce_out<<<(B * OUT / 4 + 255) / 256, 256, 0, stream>>>(
      (const float4*)P, (const float4*)lbl, b_o, (float4*)out,
      B * OUT / 4, OUT / 4);
}

// Round 6
// 137.735 us; speedup vs baseline: 1.1599x; 1.1599x over previous
//
#include <hip/hip_runtime.h>
#include <hip/hip_bf16.h>

// Net_27358941675610: the 50-step scan collapses to its fixed point:
//   R   = 0.35*sigmoid((6/7)*(psp^T @ W_h^T + b_h))            [4096,2048]
//   out = 0.35*sigmoid(0.75*(R @ W_o^T + b_o) + 0.125*label)   [4096,512]
// (0.3^50 / 0.2^50 transients < 1e-25.) Inputs fp32, output fp32.
// R6: fix R5's GEMM2 staging offset bug (c*1024 elements -> c*512; chunk is
// 512 ELEMENTS = 1024 bytes; wave3/c1 was writing past sA into sB).

typedef __bf16 bf16_t;
typedef __bf16 bf16x8 __attribute__((ext_vector_type(8)));
typedef __bf16 bf16x4v __attribute__((ext_vector_type(4)));
typedef float f32x4 __attribute__((ext_vector_type(4)));

#define GLD_TO_LDS16(gp, lp)                                            \
  __builtin_amdgcn_global_load_lds(                                     \
      (__attribute__((address_space(1))) void*)(void*)(gp),             \
      (__attribute__((address_space(3))) void*)(lp), 16, 0, 0)

// ---- psp fp32 [R][C] -> pspT bf16 [C][R], 64x64 tiles --------------------
__global__ __launch_bounds__(256) void transpose_cvt(
    const float* __restrict__ in, bf16_t* __restrict__ out, int R, int C) {
  __shared__ float tile[64][65];
  const int tx = threadIdx.x & 63;
  const int ty = threadIdx.x >> 6;
  const int r0 = blockIdx.y * 64;
  const int c0 = blockIdx.x * 64;
#pragma unroll
  for (int i = 0; i < 16; ++i) {
    const int r = ty + i * 4;
    tile[r][tx] = in[(size_t)(r0 + r) * C + c0 + tx];
  }
  __syncthreads();
#pragma unroll
  for (int i = 0; i < 16; ++i) {
    const int r = ty + i * 4;
    out[(size_t)(c0 + r) * R + r0 + tx] = (bf16_t)tile[tx][r];
  }
}

// ---- both weight matrices fp32 -> bf16, one launch -----------------------
__global__ __launch_bounds__(256) void cvt2_f32_bf16(
    const float4* __restrict__ w1, bf16x4v* __restrict__ o1, int n1,
    const float4* __restrict__ w2, bf16x4v* __restrict__ o2, int n2) {
  const int i = blockIdx.x * 256 + threadIdx.x;
  const float4 v = (i < n1) ? w1[i] : w2[i - n1];
  bf16x4v o;
  o.x = (bf16_t)v.x; o.y = (bf16_t)v.y; o.z = (bf16_t)v.z; o.w = (bf16_t)v.w;
  if (i < n1) o1[i] = o;
  else if (i - n1 < n2) o2[i - n1] = o;
}

// ---- GEMM1: R(bf16)[M,N] = 0.35*sigmoid(6/7*(A @ Bt^T + bias)) -----------
// 128x128 tile, 8 waves of 64x32, BK=32, XOR bank swizzle (R4, proven).
__global__ __launch_bounds__(512, 4) void gemm1_nt(
    const bf16_t* __restrict__ A, const bf16_t* __restrict__ Bt,
    const float* __restrict__ bias, bf16_t* __restrict__ C,
    int M, int N, int K) {
  constexpr int BK = 32;
  constexpr int WTM = 4, WTN = 2;
  __shared__ __align__(16) bf16_t sA[128 * BK];
  __shared__ __align__(16) bf16_t sB[128 * BK];

  const int tid = threadIdx.x;
  const int wave = tid >> 6;
  const int lane = tid & 63;
  const int bm = blockIdx.x * 128;
  const int bn = blockIdx.y * 128;
  const int wm = (wave & 1) * 64;
  const int wn = (wave >> 1) * 32;

  f32x4 acc[WTM][WTN] = {};

  const int arow = wave * 16 + (lane >> 2);         // row in 128-row tile
  const int sseg = (lane & 3) ^ ((arow >> 1) & 3);  // swizzled 16B segment
  const bf16_t* Ag = A + (size_t)(bm + arow) * K + sseg * 8;
  const bf16_t* Bg = Bt + (size_t)(bn + arow) * K + sseg * 8;
  bf16_t* sAw = sA + wave * (16 * BK);
  bf16_t* sBw = sB + wave * (16 * BK);

  const int fr = lane & 15;
  const int q = lane >> 4;

  for (int k0 = 0; k0 < K; k0 += BK) {
    GLD_TO_LDS16(Ag + k0, sAw);
    GLD_TO_LDS16(Bg + k0, sBw);
    __syncthreads();

    bf16x8 af[WTM], bfr[WTN];
#pragma unroll
    for (int i = 0; i < WTM; ++i) {
      const int rr = wm + i * 16 + fr;
      af[i] = *(const bf16x8*)(sA + rr * BK + ((q ^ ((rr >> 1) & 3)) * 8));
    }
#pragma unroll
    for (int j = 0; j < WTN; ++j) {
      const int rr = wn + j * 16 + fr;
      bfr[j] = *(const bf16x8*)(sB + rr * BK + ((q ^ ((rr >> 1) & 3)) * 8));
    }
#pragma unroll
    for (int i = 0; i < WTM; ++i)
#pragma unroll
      for (int j = 0; j < WTN; ++j)
        acc[i][j] =
            __builtin_amdgcn_mfma_f32_16x16x32_bf16(af[i], bfr[j], acc[i][j], 0, 0, 0);
    __syncthreads();
  }

  const int cm0 = (lane >> 4) * 4;
#pragma unroll
  for (int j = 0; j < WTN; ++j) {
    const int gn = bn + wn + j * 16 + fr;
    const float bj = bias[gn];
#pragma unroll
    for (int i = 0; i < WTM; ++i) {
#pragma unroll
      for (int r = 0; r < 4; ++r) {
        const int gm = bm + wm + i * 16 + cm0 + r;
        const float z = 0.8571428571428571f * (acc[i][j][r] + bj);
        C[(size_t)gm * N + gn] = (bf16_t)(0.35f / (1.0f + __expf(-z)));
      }
    }
  }
}

// ---- GEMM2: out(fp32) = 0.35*sigmoid(0.75*(R @ Wo^T + b_o) + 0.125*lbl) --
// 64x64 tile, BK=64, 4 waves of 32x32, grid 512 blocks (2/CU), no atomics.
// LDS slot (row, s) holds global segment s ^ (row & 7)  -> 2-way max.
// Chunk layout: 8 rows x 128 B = 1024 B = 512 ELEMENTS (R5 bug: used 1024).
__global__ __launch_bounds__(256, 4) void gemm2_nt(
    const bf16_t* __restrict__ A, const bf16_t* __restrict__ Bt,
    const float* __restrict__ bias, const float* __restrict__ lbl,
    float* __restrict__ out, int M, int N, int K) {
  constexpr int BK = 64;
  __shared__ __align__(16) bf16_t sA[64 * BK];
  __shared__ __align__(16) bf16_t sB[64 * BK];

  const int tid = threadIdx.x;
  const int wave = tid >> 6;  // 0..3
  const int lane = tid & 63;
  const int bm = blockIdx.x * 64;
  const int bn = blockIdx.y * 64;
  const int wm = (wave & 1) * 32;
  const int wn = (wave >> 1) * 32;

  f32x4 acc[2][2] = {};

  // staging: lane l of a chunk -> LDS offset l*16 B = row (l>>3), seg (l&7)
  const int srow8 = lane >> 3;  // 0..7 row within 8-row chunk
  const int sseg0 = lane & 7;   // LDS slot segment
  // wave w covers rows w*16..w*16+15 = chunks (w*2) and (w*2+1); each chunk
  // is 512 elements. Wave base = w*1024 elements.
  bf16_t* sAw = sA + wave * 1024;
  bf16_t* sBw = sB + wave * 1024;

  const int fr = lane & 15;
  const int qh = lane >> 4;  // 0..3

  for (int k0 = 0; k0 < K; k0 += BK) {
#pragma unroll
    for (int c = 0; c < 2; ++c) {
      const int row = (wave * 2 + c) * 8 + srow8;
      const int gseg = sseg0 ^ (row & 7);  // global segment for this slot
      GLD_TO_LDS16(A + (size_t)(bm + row) * K + k0 + gseg * 8,
                   sAw + c * 512);
      GLD_TO_LDS16(Bt + (size_t)(bn + row) * K + k0 + gseg * 8,
                   sBw + c * 512);
    }
    __syncthreads();

#pragma unroll
    for (int ks = 0; ks < 2; ++ks) {  // two 16x16x32 k-steps per BK
      const int q = ks * 4 + qh;      // 16B segment index 0..7
      bf16x8 af[2], bfr[2];
#pragma unroll
      for (int i = 0; i < 2; ++i) {
        const int rr = wm + i * 16 + fr;
        af[i] = *(const bf16x8*)(sA + rr * BK + ((q ^ (rr & 7)) * 8));
      }
#pragma unroll
      for (int j = 0; j < 2; ++j) {
        const int rr = wn + j * 16 + fr;
        bfr[j] = *(const bf16x8*)(sB + rr * BK + ((q ^ (rr & 7)) * 8));
      }
#pragma unroll
      for (int i = 0; i < 2; ++i)
#pragma unroll
        for (int j = 0; j < 2; ++j)
          acc[i][j] = __builtin_amdgcn_mfma_f32_16x16x32_bf16(
              af[i], bfr[j], acc[i][j], 0, 0, 0);
    }
    __syncthreads();
  }

  const int cm0 = (lane >> 4) * 4;
#pragma unroll
  for (int j = 0; j < 2; ++j) {
    const int gn = bn + wn + j * 16 + fr;
    const float bj = bias[gn];
#pragma unroll
    for (int i = 0; i < 2; ++i) {
#pragma unroll
      for (int r = 0; r < 4; ++r) {
        const int gm = bm + wm + i * 16 + cm0 + r;
        const float z =
            0.75f * (acc[i][j][r] + bj) + 0.125f * lbl[(size_t)gm * N + gn];
        out[(size_t)gm * N + gn] = 0.35f / (1.0f + __expf(-z));
      }
    }
  }
}

extern "C" void kernel_launch(void* const* d_in, const int* in_sizes, int n_in,
                              void* d_out, int out_size, void* d_ws, size_t ws_size,
                              hipStream_t stream) {
  constexpr int IN = 1024, HID = 2048, OUT = 512, B = 4096;
  const float* psp = (const float*)d_in[0];   // [IN, B]
  const float* lbl = (const float*)d_in[1];   // [B, OUT]
  const float* W_h = (const float*)d_in[2];   // [HID, IN]
  const float* b_h = (const float*)d_in[3];   // [HID]
  const float* W_o = (const float*)d_in[4];   // [OUT, HID]
  const float* b_o = (const float*)d_in[5];   // [OUT]
  float* out = (float*)d_out;                 // [B, OUT] fp32

  bf16_t* Whb = (bf16_t*)d_ws;                 // [HID, IN]  4 MB
  bf16_t* Wob = Whb + (size_t)HID * IN;        // [OUT, HID] 2 MB
  bf16_t* pspT = Wob + (size_t)OUT * HID;      // [B, IN]    8 MB
  bf16_t* Rm = pspT + (size_t)B * IN;          // [B, HID]  16 MB

  // psp [IN,B] fp32 -> pspT [B,IN] bf16
  transpose_cvt<<<dim3(B / 64, IN / 64), 256, 0, stream>>>(psp, pspT, IN, B);
  // both weights fp32 -> bf16
  {
    const int n1 = HID * IN / 4, n2 = OUT * HID / 4;
    cvt2_f32_bf16<<<(n1 + n2 + 255) / 256, 256, 0, stream>>>(
        (const float4*)W_h, (bf16x4v*)Whb, n1,
        (const float4*)W_o, (bf16x4v*)Wob, n2);
  }
  // R = 0.35*sigmoid((6/7)*(pspT @ W_h^T + b_h))  [bf16]
  gemm1_nt<<<dim3(B / 128, HID / 128), 512, 0, stream>>>(
      pspT, Whb, b_h, Rm, B, HID, IN);
  // out = 0.35*sigmoid(0.75*(R @ W_o^T + b_o) + 0.125*label)  [fp32]
  gemm2_nt<<<dim3(B / 64, OUT / 64), 256, 0, stream>>>(
      Rm, Wob, b_o, lbl, out, B, OUT, HID);
}

// Round 8
// 136.251 us; speedup vs baseline: 1.1725x; 1.0109x over previous
//
#include <hip/hip_runtime.h>
#include <hip/hip_bf16.h>

// Net_27358941675610: the 50-step scan collapses to its fixed point:
//   R   = 0.35*sigmoid((6/7)*(psp^T @ W_h^T + b_h))            [4096,2048]
//   out = 0.35*sigmoid(0.75*(R @ W_o^T + b_o) + 0.125*label)   [4096,512]
// Inputs fp32, output fp32. Internal: bf16 MFMA, fp32 acc.
// R8: back to single-buffer 2-barrier K-loop (R7 dbuf was flaky: barrier may
// not drain prefetch vmcnt -> rare stale-LDS race). GEMM1 re-tiled to 4 waves
// x 64x64 wave-tile (2 MFMA per ds_read_b128, was 1.33) -- the real
// bottleneck is LDS read throughput, not global latency (dbuf gained 3.5us).

typedef __bf16 bf16_t;
typedef __bf16 bf16x8 __attribute__((ext_vector_type(8)));
typedef __bf16 bf16x4v __attribute__((ext_vector_type(4)));
typedef float f32x4 __attribute__((ext_vector_type(4)));

#define GLD_TO_LDS16(gp, lp)                                            \
  __builtin_amdgcn_global_load_lds(                                     \
      (__attribute__((address_space(1))) void*)(void*)(gp),             \
      (__attribute__((address_space(3))) void*)(lp), 16, 0, 0)

// ---- psp fp32 [R][C] -> pspT bf16 [C][R], 64x64 tiles --------------------
__global__ __launch_bounds__(256) void transpose_cvt(
    const float* __restrict__ in, bf16_t* __restrict__ out, int R, int C) {
  __shared__ float tile[64][65];
  const int tx = threadIdx.x & 63;
  const int ty = threadIdx.x >> 6;
  const int r0 = blockIdx.y * 64;
  const int c0 = blockIdx.x * 64;
#pragma unroll
  for (int i = 0; i < 16; ++i) {
    const int r = ty + i * 4;
    tile[r][tx] = in[(size_t)(r0 + r) * C + c0 + tx];
  }
  __syncthreads();
#pragma unroll
  for (int i = 0; i < 16; ++i) {
    const int r = ty + i * 4;
    out[(size_t)(c0 + r) * R + r0 + tx] = (bf16_t)tile[tx][r];
  }
}

// ---- both weight matrices fp32 -> bf16, one launch -----------------------
__global__ __launch_bounds__(256) void cvt2_f32_bf16(
    const float4* __restrict__ w1, bf16x4v* __restrict__ o1, int n1,
    const float4* __restrict__ w2, bf16x4v* __restrict__ o2, int n2) {
  const int i = blockIdx.x * 256 + threadIdx.x;
  const float4 v = (i < n1) ? w1[i] : w2[i - n1];
  bf16x4v o;
  o.x = (bf16_t)v.x; o.y = (bf16_t)v.y; o.z = (bf16_t)v.z; o.w = (bf16_t)v.w;
  if (i < n1) o1[i] = o;
  else if (i - n1 < n2) o2[i - n1] = o;
}

// ---- GEMM1: R(bf16) = 0.35*sigmoid(6/7*(A @ Bt^T + bias)) ----------------
// 128x128 tile, 4 waves of 64x64 (WTM=WTN=4), BK=64, single-buffer LDS 32KB.
// Staging: 8-row chunks; LDS slot (row,s) holds global seg s^(row&7).
__global__ __launch_bounds__(256, 2) void gemm1_nt(
    const bf16_t* __restrict__ A, const bf16_t* __restrict__ Bt,
    const float* __restrict__ bias, bf16_t* __restrict__ C,
    int M, int N, int K) {
  constexpr int BK = 64;
  __shared__ __align__(16) bf16_t sA[128 * BK];
  __shared__ __align__(16) bf16_t sB[128 * BK];

  const int tid = threadIdx.x;
  const int wave = tid >> 6;  // 0..3
  const int lane = tid & 63;
  const int bm = blockIdx.x * 128;
  const int bn = blockIdx.y * 128;
  const int wm = (wave & 1) * 64;
  const int wn = (wave >> 1) * 64;

  f32x4 acc[4][4] = {};

  // wave w stages A rows w*32..w*32+31 and B rows w*32..w*32+31 (4 chunks
  // of 8 rows each). lane l -> chunk row l>>3, LDS seg l&7,
  // global seg (l&7)^(l>>3)  (row&7 == l>>3 since chunk bases are 8-aligned).
  const int srow8 = lane >> 3;
  const int gseg = (lane & 7) ^ srow8;
  const bf16_t* Ag = A + (size_t)(bm + wave * 32 + srow8) * K + gseg * 8;
  const bf16_t* Bg = Bt + (size_t)(bn + wave * 32 + srow8) * K + gseg * 8;
  const int dst = wave * 2048;  // 4 chunks x 512 elements

  const int fr = lane & 15;
  const int qh = lane >> 4;  // 0..3

  for (int k0 = 0; k0 < K; k0 += BK) {
#pragma unroll
    for (int c = 0; c < 4; ++c) {
      GLD_TO_LDS16(Ag + (size_t)(c * 8) * K + k0, sA + dst + c * 512);
      GLD_TO_LDS16(Bg + (size_t)(c * 8) * K + k0, sB + dst + c * 512);
    }
    __syncthreads();  // publishes staged tiles (vmcnt drained at barrier)

#pragma unroll
    for (int ks = 0; ks < 2; ++ks) {
      const int q = ks * 4 + qh;  // 16B segment 0..7
      bf16x8 av[4], bv[4];
#pragma unroll
      for (int i = 0; i < 4; ++i) {
        const int rr = wm + i * 16 + fr;
        av[i] = *(const bf16x8*)(sA + rr * BK + ((q ^ (rr & 7)) * 8));
      }
#pragma unroll
      for (int j = 0; j < 4; ++j) {
        const int rr = wn + j * 16 + fr;
        bv[j] = *(const bf16x8*)(sB + rr * BK + ((q ^ (rr & 7)) * 8));
      }
#pragma unroll
      for (int i = 0; i < 4; ++i)
#pragma unroll
        for (int j = 0; j < 4; ++j)
          acc[i][j] = __builtin_amdgcn_mfma_f32_16x16x32_bf16(
              av[i], bv[j], acc[i][j], 0, 0, 0);
    }
    __syncthreads();  // protects buffer reuse next iteration
  }

  // epilogue: C/D layout col = lane&15, row = (lane>>4)*4 + r  (m89)
  const int cm0 = (lane >> 4) * 4;
#pragma unroll
  for (int j = 0; j < 4; ++j) {
    const int gn = bn + wn + j * 16 + fr;
    const float bj = bias[gn];
#pragma unroll
    for (int i = 0; i < 4; ++i) {
#pragma unroll
      for (int r = 0; r < 4; ++r) {
        const int gm = bm + wm + i * 16 + cm0 + r;
        const float z = 0.8571428571428571f * (acc[i][j][r] + bj);
        C[(size_t)gm * N + gn] = (bf16_t)(0.35f / (1.0f + __expf(-z)));
      }
    }
  }
}

// ---- GEMM2: out(fp32) = 0.35*sigmoid(0.75*(R @ Wo^T + b_o) + 0.125*lbl) --
// R6 version verbatim (proven). 64x64 tile, BK=64, 4 waves of 32x32.
__global__ __launch_bounds__(256, 4) void gemm2_nt(
    const bf16_t* __restrict__ A, const bf16_t* __restrict__ Bt,
    const float* __restrict__ bias, const float* __restrict__ lbl,
    float* __restrict__ out, int M, int N, int K) {
  constexpr int BK = 64;
  __shared__ __align__(16) bf16_t sA[64 * BK];
  __shared__ __align__(16) bf16_t sB[64 * BK];

  const int tid = threadIdx.x;
  const int wave = tid >> 6;  // 0..3
  const int lane = tid & 63;
  const int bm = blockIdx.x * 64;
  const int bn = blockIdx.y * 64;
  const int wm = (wave & 1) * 32;
  const int wn = (wave >> 1) * 32;

  f32x4 acc[2][2] = {};

  const int srow8 = lane >> 3;
  const int sseg0 = lane & 7;
  bf16_t* sAw = sA + wave * 1024;
  bf16_t* sBw = sB + wave * 1024;

  const int fr = lane & 15;
  const int qh = lane >> 4;

  for (int k0 = 0; k0 < K; k0 += BK) {
#pragma unroll
    for (int c = 0; c < 2; ++c) {
      const int row = (wave * 2 + c) * 8 + srow8;
      const int gseg = sseg0 ^ (row & 7);
      GLD_TO_LDS16(A + (size_t)(bm + row) * K + k0 + gseg * 8,
                   sAw + c * 512);
      GLD_TO_LDS16(Bt + (size_t)(bn + row) * K + k0 + gseg * 8,
                   sBw + c * 512);
    }
    __syncthreads();

#pragma unroll
    for (int ks = 0; ks < 2; ++ks) {
      const int q = ks * 4 + qh;
      bf16x8 av[2], bv[2];
#pragma unroll
      for (int i = 0; i < 2; ++i) {
        const int rr = wm + i * 16 + fr;
        av[i] = *(const bf16x8*)(sA + rr * BK + ((q ^ (rr & 7)) * 8));
      }
#pragma unroll
      for (int j = 0; j < 2; ++j) {
        const int rr = wn + j * 16 + fr;
        bv[j] = *(const bf16x8*)(sB + rr * BK + ((q ^ (rr & 7)) * 8));
      }
#pragma unroll
      for (int i = 0; i < 2; ++i)
#pragma unroll
        for (int j = 0; j < 2; ++j)
          acc[i][j] = __builtin_amdgcn_mfma_f32_16x16x32_bf16(
              av[i], bv[j], acc[i][j], 0, 0, 0);
    }
    __syncthreads();
  }

  const int cm0 = (lane >> 4) * 4;
#pragma unroll
  for (int j = 0; j < 2; ++j) {
    const int gn = bn + wn + j * 16 + fr;
    const float bj = bias[gn];
#pragma unroll
    for (int i = 0; i < 2; ++i) {
#pragma unroll
      for (int r = 0; r < 4; ++r) {
        const int gm = bm + wm + i * 16 + cm0 + r;
        const float z =
            0.75f * (acc[i][j][r] + bj) + 0.125f * lbl[(size_t)gm * N + gn];
        out[(size_t)gm * N + gn] = 0.35f / (1.0f + __expf(-z));
      }
    }
  }
}

extern "C" void kernel_launch(void* const* d_in, const int* in_sizes, int n_in,
                              void* d_out, int out_size, void* d_ws, size_t ws_size,
                              hipStream_t stream) {
  constexpr int IN = 1024, HID = 2048, OUT = 512, B = 4096;
  const float* psp = (const float*)d_in[0];   // [IN, B]
  const float* lbl = (const float*)d_in[1];   // [B, OUT]
  const float* W_h = (const float*)d_in[2];   // [HID, IN]
  const float* b_h = (const float*)d_in[3];   // [HID]
  const float* W_o = (const float*)d_in[4];   // [OUT, HID]
  const float* b_o = (const float*)d_in[5];   // [OUT]
  float* out = (float*)d_out;                 // [B, OUT] fp32

  bf16_t* Whb = (bf16_t*)d_ws;                 // [HID, IN]  4 MB
  bf16_t* Wob = Whb + (size_t)HID * IN;        // [OUT, HID] 2 MB
  bf16_t* pspT = Wob + (size_t)OUT * HID;      // [B, IN]    8 MB
  bf16_t* Rm = pspT + (size_t)B * IN;          // [B, HID]  16 MB

  transpose_cvt<<<dim3(B / 64, IN / 64), 256, 0, stream>>>(psp, pspT, IN, B);
  {
    const int n1 = HID * IN / 4, n2 = OUT * HID / 4;
    cvt2_f32_bf16<<<(n1 + n2 + 255) / 256, 256, 0, stream>>>(
        (const float4*)W_h, (bf16x4v*)Whb, n1,
        (const float4*)W_o, (bf16x4v*)Wob, n2);
  }
  gemm1_nt<<<dim3(B / 128, HID / 128), 256, 0, stream>>>(
      pspT, Whb, b_h, Rm, B, HID, IN);
  gemm2_nt<<<dim3(B / 64, OUT / 64), 256, 0, stream>>>(
      Rm, Wob, b_o, lbl, out, B, OUT, HID);
}